// Round 4
// baseline (27.132 us; speedup 1.0000x reference)
//
#include <hip/hip_runtime.h>
#include <stdint.h>

// Problem constants (match reference)
constexpr int NB = 256;      // batch
constexpr int NS = 64;       // sequence
constexpr int NIB = 32;      // bits per token
constexpr int NH = 4;        // heads
constexpr int SIMB = 12;     // sim address bits
constexpr int VALB = 10;     // val address bits
constexpr int OUTB = 12;     // out address bits

// Packed table layout in ws (uint32 words) — round-2 proven layout
constexpr int TOK_WORDS = NB * NS;        // 16384 : tokens[b,s] -> 32 bits
constexpr int SIM_WORDS = NH * 128;       // 512   : sim_mem[h] -> 4096 bits
constexpr int VAL_WORDS = NH * NIB * 32;  // 4096  : val_mem[h,n] -> 1024 bits
constexpr int AGG_WORDS = NH * NIB * 3;   // 384   : agg_mem[h,n] -> 65 bits (in 96)

__device__ __forceinline__ uint32_t pack32_f4(const float* __restrict__ p) {
    uint32_t v = 0;
    const float4* q = reinterpret_cast<const float4*>(p);
#pragma unroll
    for (int k = 0; k < 8; ++k) {
        float4 f = q[k];
        v |= (uint32_t)(f.x > 0.5f) << (4 * k + 0);
        v |= (uint32_t)(f.y > 0.5f) << (4 * k + 1);
        v |= (uint32_t)(f.z > 0.5f) << (4 * k + 2);
        v |= (uint32_t)(f.w > 0.5f) << (4 * k + 3);
    }
    return v;
}

// ---- K1: round-2 proven pack kernel (tokens + sim + val + agg), verbatim ----
__global__ __launch_bounds__(256) void pack_kernel(
    const int* __restrict__ tokens, const float* __restrict__ sim_mem,
    const float* __restrict__ val_mem, const float* __restrict__ agg_mem,
    uint32_t* __restrict__ ws)
{
    int tid = blockIdx.x * blockDim.x + threadIdx.x;
    uint32_t* wtok = ws;
    uint32_t* wsim = ws + TOK_WORDS;
    uint32_t* wval = wsim + SIM_WORDS;
    uint32_t* wagg = wval + VAL_WORDS;
    if (tid < TOK_WORDS) {
        const int* p = tokens + tid * NIB;
        uint32_t v = 0;
#pragma unroll
        for (int c = 0; c < NIB; ++c) v |= (uint32_t)(p[c] & 1) << c;
        wtok[tid] = v;
    }
    if (tid < SIM_WORDS) wsim[tid] = pack32_f4(sim_mem + tid * 32);
    if (tid < VAL_WORDS) wval[tid] = pack32_f4(val_mem + tid * 32);
    if (tid < AGG_WORDS) {
        int hn = tid / 3, w = tid % 3;
        uint32_t v = 0;
        for (int c = 0; c < 32; ++c) {
            int cnt = w * 32 + c;
            if (cnt < NS + 1) v |= (uint32_t)(agg_mem[hn * (NS + 1) + cnt] > 0.5f) << c;
        }
        wagg[tid] = v;
    }
}

// ---- K2: fused attend + proj + agg + out ----
// block = (b, half of i-range); 512 threads = 8 waves; lane = j.
// Identical to round-3 fused kernel EXCEPT s_tok comes from proven wtok.
__global__ __launch_bounds__(512) void fused_kernel(
    const uint32_t* __restrict__ ws,
    const int* __restrict__ sim_conn,    // [H][12]
    const int* __restrict__ val_conn,    // [H][IB][10]
    const int* __restrict__ out_conn,    // [IB][12]
    const float* __restrict__ out_mem,   // [IB][4096]
    float* __restrict__ out)             // [B][S][IB]
{
    const int b = blockIdx.x >> 1, half = blockIdx.x & 1;
    const int tid = threadIdx.x, lane = tid & 63, wave = tid >> 6;

    __shared__ uint32_t s_tok[NS];
    __shared__ uint32_t s_sim[SIM_WORDS];         // [h][128]
    __shared__ uint32_t s_val[VAL_WORDS];         // [h][n][32]
    __shared__ uint32_t s_agg[AGG_WORDS];         // [h][n][3]
    __shared__ int      s_sconn[NH * SIMB];       // 48
    __shared__ int      s_vconn[NH * NIB * VALB]; // 1280
    __shared__ int      s_oconn[NIB * OUTB];      // 384
    __shared__ uint32_t s_ip[NS][NH];
    __shared__ uint32_t s_jp[NS][NH];
    __shared__ uint64_t s_att[32][NH];            // this half's i
    __shared__ uint64_t s_proj[NH][NIB];
    __shared__ uint32_t s_comb[32][NH];

    const uint32_t* wtok = ws;
    const uint32_t* wsim = ws + TOK_WORDS;
    const uint32_t* wval = wsim + SIM_WORDS;
    const uint32_t* wagg = wval + VAL_WORDS;

    // ---- stage 0: stage packed tables + conns + this b's packed tokens ----
    if (tid < NS)        s_tok[tid] = wtok[b * NS + tid];
    if (tid < SIM_WORDS) s_sim[tid] = wsim[tid];
#pragma unroll
    for (int r = 0; r < 8; ++r) s_val[r * 512 + tid] = wval[r * 512 + tid];
    if (tid < AGG_WORDS) s_agg[tid] = wagg[tid];
    if (tid < NH * SIMB) s_sconn[tid] = sim_conn[tid];
    for (int i = tid; i < NH * NIB * VALB; i += 512) s_vconn[i] = val_conn[i];
    if (tid < NIB * OUTB) s_oconn[tid] = out_conn[tid];
    __syncthreads();

    // per-lane 38-bit val_in vector: bit c == val_in[j=lane][c]
    const uint32_t tkj = s_tok[lane];
    const uint32_t rev6 = __brev((uint32_t)lane) >> 26;
    const uint64_t V = (uint64_t)tkj | ((uint64_t)rev6 << 32);

    // ---- stage 2 (waves 4-7, thread t2=(s,h)): split sim addr into i/j parts ----
    if (tid >= 256) {
        const int t2 = tid - 256;
        const int s = t2 >> 2, h = t2 & 3;
        const uint32_t tk = s_tok[s];
        uint32_t ip = 0, jp = 0;
#pragma unroll
        for (int t = 0; t < SIMB; ++t) {
            int c = s_sconn[h * SIMB + t];
            uint32_t w = 1u << (SIMB - 1 - t);
            if (c < 32)      ip += ((tk >> c) & 1u) * w;                    // qb
            else if (c < 64) jp += ((tk >> (c - 32)) & 1u) * w;             // kb
            else if (c < 70) ip += (((uint32_t)s >> (69 - c)) & 1u) * w;    // qp
            else             jp += (((uint32_t)s >> (75 - c)) & 1u) * w;    // kp
        }
        s_ip[s][h] = ip;
        s_jp[s][h] = jp;
    }

    // ---- stage 3: proj masks via ballot. wave handles 16 of 128 (h,n). ----
    for (int r = 0; r < 16; ++r) {
        const int hn = wave * 16 + r;
        const int* conn = s_vconn + hn * VALB;
        uint32_t addr = 0;
#pragma unroll
        for (int t = 0; t < VALB; ++t)
            addr += (uint32_t)((V >> conn[t]) & 1ull) << (VALB - 1 - t);
        uint32_t bit = (s_val[hn * 32 + (addr >> 5)] >> (addr & 31)) & 1u;
        uint64_t m = __ballot((int)bit);
        if (lane == 0) s_proj[hn >> 5][hn & 31] = m;
    }
    __syncthreads();   // covers stage 2 + stage 3 writes

    // ---- stage 4: attend masks via ballot. wave handles 16 of 128 (il,h). ----
    for (int r = 0; r < 16; ++r) {
        const int idx = wave * 16 + r;
        const int il = idx >> 2, h = idx & 3;
        const int ig = half * 32 + il;
        uint32_t addr = s_ip[ig][h] + s_jp[lane][h];
        uint32_t bit = (s_sim[h * 128 + (addr >> 5)] >> (addr & 31)) & 1u;
        uint64_t m = __ballot((int)bit);
        if (lane == 0) s_att[il][h] = m & (~0ull >> (63 - ig));   // causal
    }
    __syncthreads();

    // ---- stage 5: counts -> agg bit -> comb word. thread = (il, h, quarter). ----
    {
        const int il = tid >> 4, h = (tid >> 2) & 3, q = tid & 3;
        const uint64_t am = s_att[il][h];
        uint32_t word = 0;
#pragma unroll
        for (int nn = 0; nn < 8; ++nn) {
            const int n = q * 8 + nn;
            int cnt = __popcll(am & s_proj[h][n]);
            uint32_t bit = (s_agg[(h * NIB + n) * 3 + (cnt >> 5)] >> (cnt & 31)) & 1u;
            word |= bit << n;
        }
        word = (am != 0ull) ? word : 0u;     // n_att > 0.5 gate (quad-uniform)
        word |= __shfl_xor(word, 1);
        word |= __shfl_xor(word, 2);
        if (q == 0) s_comb[il][h] = word;
    }
    __syncthreads();

    // ---- stage 6: out address gather + final float lookup ----
    {
        const int n = tid & 31;
        const int ii = tid >> 5;                 // 0..15
        int conn[OUTB];
#pragma unroll
        for (int t = 0; t < OUTB; ++t) conn[t] = s_oconn[n * OUTB + t];
        const float* om = out_mem + n * 4096;
#pragma unroll
        for (int k = 0; k < 2; ++k) {
            const int il = ii + k * 16;
            uint64_t lo = (uint64_t)s_comb[il][0] | ((uint64_t)s_comb[il][1] << 32);
            uint64_t hi = (uint64_t)s_comb[il][2] | ((uint64_t)s_comb[il][3] << 32);
            uint32_t addr = 0;
#pragma unroll
            for (int t = 0; t < OUTB; ++t) {
                int c = conn[t];
                uint64_t w = (c < 64) ? lo : hi;
                addr += (uint32_t)((w >> (c & 63)) & 1ull) << (OUTB - 1 - t);
            }
            out[(b * NS + half * 32 + il) * NIB + n] = om[addr];
        }
    }
}

// ---- fallback: monolithic kernel (used only if ws is too small) ----
__global__ __launch_bounds__(256) void ram_main_fallback(
    const int* __restrict__ tokens,
    const int* __restrict__ sim_conn, const float* __restrict__ sim_mem,
    const int* __restrict__ val_conn, const float* __restrict__ val_mem,
    const float* __restrict__ agg_mem,
    const int* __restrict__ out_conn, const float* __restrict__ out_mem,
    float* __restrict__ out)
{
    __shared__ uint32_t s_sim[SIM_WORDS];
    __shared__ uint32_t s_val[VAL_WORDS];
    __shared__ uint32_t s_agg[AGG_WORDS];
    __shared__ uint32_t s_tok[NS];
    __shared__ uint32_t s_ipart[NS][NH];
    __shared__ uint32_t s_jpart[NS][NH];
    __shared__ uint64_t s_att[NS][NH];
    __shared__ uint64_t s_proj[NH][NIB];
    __shared__ uint32_t s_comb[NS][NH];

    const int tid = threadIdx.x;
    const int b = blockIdx.x;

    for (int i = tid; i < SIM_WORDS; i += 256) s_sim[i] = pack32_f4(sim_mem + i * 32);
    for (int i = tid; i < VAL_WORDS; i += 256) s_val[i] = pack32_f4(val_mem + i * 32);
    for (int i = tid; i < AGG_WORDS; i += 256) {
        int hn = i / 3, w = i % 3;
        uint32_t v = 0;
        for (int c = 0; c < 32; ++c) {
            int cnt = w * 32 + c;
            if (cnt < NS + 1) v |= (uint32_t)(agg_mem[hn * (NS + 1) + cnt] > 0.5f) << c;
        }
        s_agg[i] = v;
    }
    if (tid < NS) {
        const int* p = tokens + (b * NS + tid) * NIB;
        uint32_t v = 0;
#pragma unroll
        for (int c = 0; c < NIB; ++c) v |= (uint32_t)(p[c] & 1) << c;
        s_tok[tid] = v;
    }
    __syncthreads();

    {
        int s = tid >> 2, h = tid & 3;
        uint32_t tk = s_tok[s];
        uint32_t ip = 0, jp = 0;
#pragma unroll
        for (int t = 0; t < SIMB; ++t) {
            int c = sim_conn[h * SIMB + t];
            uint32_t w = 1u << (SIMB - 1 - t);
            if (c < 32)      ip += ((tk >> c) & 1u) * w;
            else if (c < 64) jp += ((tk >> (c - 32)) & 1u) * w;
            else if (c < 70) ip += (((uint32_t)s >> (69 - c)) & 1u) * w;
            else             jp += (((uint32_t)s >> (75 - c)) & 1u) * w;
        }
        s_ipart[s][h] = ip;
        s_jpart[s][h] = jp;
    }
    __syncthreads();

    if (tid < NH * NIB) {
        int h = tid >> 5, n = tid & 31;
        int conn[VALB];
#pragma unroll
        for (int t = 0; t < VALB; ++t) conn[t] = val_conn[(h * NIB + n) * VALB + t];
        uint64_t mask = 0;
        for (int j = 0; j < NS; ++j) {
            uint32_t tk = s_tok[j];
            uint32_t addr = 0;
#pragma unroll
            for (int t = 0; t < VALB; ++t) {
                int c = conn[t];
                uint32_t bit = (c < 32) ? ((tk >> c) & 1u)
                                        : (((uint32_t)j >> (37 - c)) & 1u);
                addr += bit << (VALB - 1 - t);
            }
            uint32_t bit = (s_val[(h * NIB + n) * 32 + (addr >> 5)] >> (addr & 31)) & 1u;
            mask |= (uint64_t)bit << j;
        }
        s_proj[h][n] = mask;
    }

    {
        int i = tid >> 2, h = tid & 3;
        uint32_t ip = s_ipart[i][h];
        uint64_t mask = 0;
        for (int j = 0; j <= i; ++j) {
            uint32_t addr = ip + s_jpart[j][h];
            uint32_t bit = (s_sim[h * 128 + (addr >> 5)] >> (addr & 31)) & 1u;
            mask |= (uint64_t)bit << j;
        }
        s_att[i][h] = mask;
    }
    __syncthreads();

    {
        int i = tid >> 2, h = tid & 3;
        uint64_t am = s_att[i][h];
        uint32_t word = 0;
        if (am) {
#pragma unroll
            for (int n = 0; n < NIB; ++n) {
                int cnt = __popcll(am & s_proj[h][n]);
                uint32_t bit = (s_agg[(h * NIB + n) * 3 + (cnt >> 5)] >> (cnt & 31)) & 1u;
                word |= bit << n;
            }
        }
        s_comb[i][h] = word;
    }
    __syncthreads();

    for (int slot = tid; slot < NS * NIB; slot += 256) {
        int i = slot >> 5;
        int n = slot & 31;
        uint32_t cw0 = s_comb[i][0], cw1 = s_comb[i][1],
                 cw2 = s_comb[i][2], cw3 = s_comb[i][3];
        uint32_t addr = 0;
#pragma unroll
        for (int t = 0; t < OUTB; ++t) {
            int c = out_conn[n * OUTB + t];
            uint32_t w = (c < 64) ? ((c < 32) ? cw0 : cw1) : ((c < 96) ? cw2 : cw3);
            addr += ((w >> (c & 31)) & 1u) << (OUTB - 1 - t);
        }
        out[(b * NS + i) * NIB + n] = out_mem[n * 4096 + addr];
    }
}

extern "C" void kernel_launch(void* const* d_in, const int* in_sizes, int n_in,
                              void* d_out, int out_size, void* d_ws, size_t ws_size,
                              hipStream_t stream) {
    const int*   tokens   = (const int*)d_in[0];
    const int*   sim_conn = (const int*)d_in[1];
    const float* sim_mem  = (const float*)d_in[2];
    const int*   val_conn = (const int*)d_in[3];
    const float* val_mem  = (const float*)d_in[4];
    const float* agg_mem  = (const float*)d_in[5];
    const int*   out_conn = (const int*)d_in[6];
    const float* out_mem  = (const float*)d_in[7];
    float* out = (float*)d_out;

    const size_t need =
        (size_t)(TOK_WORDS + SIM_WORDS + VAL_WORDS + AGG_WORDS) * sizeof(uint32_t);
    if (ws_size >= need) {
        uint32_t* ws = (uint32_t*)d_ws;
        pack_kernel<<<(TOK_WORDS + 255) / 256, 256, 0, stream>>>(tokens, sim_mem, val_mem, agg_mem, ws);
        fused_kernel<<<NB * 2, 512, 0, stream>>>(ws, sim_conn, val_conn,
                                                 out_conn, out_mem, out);
    } else {
        ram_main_fallback<<<NB, 256, 0, stream>>>(tokens, sim_conn, sim_mem, val_conn,
                                                  val_mem, agg_mem, out_conn, out_mem, out);
    }
}